// Round 3
// baseline (345.850 us; speedup 1.0000x reference)
//
#include <hip/hip_runtime.h>
#include <hip/hip_bf16.h>
#include <math.h>

#define N_NODES 20000
#define N_EDGES 320000
#define ET (N_EDGES + N_NODES)   // with self loops = 340000
#define IN_C 512
#define HEADS 8
#define HID 32
#define HH (HEADS * HID)         // 256
#define OUT_C 40
#define NEG_SLOPE 0.2f

typedef __attribute__((ext_vector_type(8))) short short8;
typedef __attribute__((ext_vector_type(4))) float floatx4;

static __device__ __forceinline__ unsigned short f2bf(float f) {
  __hip_bfloat16 h = __float2bfloat16(f);
  return *(unsigned short*)&h;
}
static __device__ __forceinline__ float bf2f_lo(unsigned int u) {
  return __uint_as_float(u << 16);
}
static __device__ __forceinline__ float bf2f_hi(unsigned int u) {
  return __uint_as_float(u & 0xFFFF0000u);
}

// ---------------- convert x -> bf16 ----------------
__global__ __launch_bounds__(256) void convert_x_kernel(
    const float* __restrict__ x, unsigned short* __restrict__ xb) {
  size_t i = ((size_t)blockIdx.x * blockDim.x + threadIdx.x) * 4;
  if (i >= (size_t)N_NODES * IN_C) return;
  float4 v = *(const float4*)(x + i);
  ushort4 o;
  o.x = f2bf(v.x); o.y = f2bf(v.y); o.z = f2bf(v.z); o.w = f2bf(v.w);
  *(ushort4*)(xb + i) = o;
}

// ---------------- convert w1 [512,256] -> bf16 transposed [256,512] ----------------
__global__ __launch_bounds__(256) void convert_w_kernel(
    const float* __restrict__ w1, unsigned short* __restrict__ wbT) {
  int id = blockIdx.x * blockDim.x + threadIdx.x;   // 131072
  if (id >= IN_C * HH) return;
  int k = id >> 8, n = id & 255;                    // coalesced read
  wbT[(size_t)n * IN_C + k] = f2bf(w1[id]);
}

// ---------------- GEMM1 (MFMA bf16): h1b = bf16(x @ w1 + b1) ----------------
#define BM 128
#define BN 64
#define BK 32
#define APAD 40   // row stride in shorts (80B, 16B-aligned)
__global__ __launch_bounds__(256) void gemm1_kernel(
    const unsigned short* __restrict__ A, const unsigned short* __restrict__ BT,
    const float* __restrict__ bias, unsigned short* __restrict__ C, int M) {
  __shared__ unsigned short As[BM][APAD];   // [128][40]
  __shared__ unsigned short Bs[BN][APAD];   // [64][40]
  const int tid = threadIdx.x;
  const int lane = tid & 63, wave = tid >> 6;
  const int wm = (wave & 1) * 64;
  const int wn = (wave >> 1) * 32;
  const int r16 = lane & 15, q = lane >> 4;
  const int rowBase = blockIdx.y * BM;
  const int colBase = blockIdx.x * BN;
  floatx4 acc[4][2] = {};

  for (int k0 = 0; k0 < IN_C; k0 += BK) {
#pragma unroll
    for (int i = 0; i < 2; i++) {
      int c = tid + i * 256;
      int row = c >> 2, kc = (c & 3) * 8;
      int arow = rowBase + row;
      float4 v = make_float4(0.f, 0.f, 0.f, 0.f);
      if (arow < M) v = *(const float4*)(A + (size_t)arow * IN_C + k0 + kc);
      *(float4*)&As[row][kc] = v;
    }
    {
      int row = tid >> 2, kc = (tid & 3) * 8;
      float4 v = *(const float4*)(BT + (size_t)(colBase + row) * IN_C + k0 + kc);
      *(float4*)&Bs[row][kc] = v;
    }
    __syncthreads();
    short8 afrag[4], bfrag[2];
#pragma unroll
    for (int mt = 0; mt < 4; mt++)
      afrag[mt] = *(const short8*)&As[wm + mt * 16 + r16][q * 8];
#pragma unroll
    for (int nt = 0; nt < 2; nt++)
      bfrag[nt] = *(const short8*)&Bs[wn + nt * 16 + r16][q * 8];
#pragma unroll
    for (int mt = 0; mt < 4; mt++)
#pragma unroll
      for (int nt = 0; nt < 2; nt++)
        acc[mt][nt] = __builtin_amdgcn_mfma_f32_16x16x32_bf16(
            afrag[mt], bfrag[nt], acc[mt][nt], 0, 0, 0);
    __syncthreads();
  }
#pragma unroll
  for (int mt = 0; mt < 4; mt++) {
#pragma unroll
    for (int nt = 0; nt < 2; nt++) {
      int col = colBase + wn + nt * 16 + r16;
      float bb = bias[col];
#pragma unroll
      for (int r = 0; r < 4; r++) {
        int row = rowBase + wm + mt * 16 + q * 4 + r;
        if (row < M) C[(size_t)row * HH + col] = f2bf(acc[mt][nt][r] + bb);
      }
    }
  }
}

// ---------------- attn1: per-node per-head dot with att vectors (bf16 h1) ----------------
__global__ __launch_bounds__(256) void attn1_kernel(
    const unsigned short* __restrict__ h1b, const float* __restrict__ asrc,
    const float* __restrict__ adst, float* __restrict__ as1, float* __restrict__ ad1) {
  int n = blockIdx.x, t = threadIdx.x;       // t = head*32 + c
  float h = bf2f_lo((unsigned int)h1b[(size_t)n * HH + t]);
  float ps = h * asrc[t];
  float pd = h * adst[t];
  for (int o = 16; o > 0; o >>= 1) {
    ps += __shfl_down(ps, o, 32);
    pd += __shfl_down(pd, o, 32);
  }
  if ((t & 31) == 0) {
    as1[n * HEADS + (t >> 5)] = ps;
    ad1[n * HEADS + (t >> 5)] = pd;
  }
}

// ---------------- CSR build (by dst) ----------------
__global__ void count_kernel(const int* __restrict__ ei, int* __restrict__ deg) {
  int e = blockIdx.x * blockDim.x + threadIdx.x;
  if (e >= ET) return;
  int dst = (e < N_EDGES) ? ei[N_EDGES + e] : (e - N_EDGES);
  atomicAdd(&deg[dst], 1);
}

#define SCAN_PER 20
__global__ __launch_bounds__(1024) void scan_kernel(
    const int* __restrict__ deg, int* __restrict__ offs, int* __restrict__ cursor) {
  __shared__ int wsum[16];
  int t = threadIdx.x;
  int base = t * SCAN_PER;
  int local[SCAN_PER];
  int s = 0;
#pragma unroll
  for (int i = 0; i < SCAN_PER; i++) {
    int idx = base + i;
    int v = (idx < N_NODES) ? deg[idx] : 0;
    local[i] = s;
    s += v;
  }
  int lane = t & 63, w = t >> 6;
  int inc = s;
  for (int o = 1; o < 64; o <<= 1) {
    int u = __shfl_up(inc, o, 64);
    if (lane >= o) inc += u;
  }
  if (lane == 63) wsum[w] = inc;
  __syncthreads();
  if (w == 0 && lane < 16) {
    int v = wsum[lane];
    for (int o = 1; o < 16; o <<= 1) {
      int u = __shfl_up(v, o, 64);
      if (lane >= o) v += u;
    }
    wsum[lane] = v;
  }
  __syncthreads();
  int waveOff = (w == 0) ? 0 : wsum[w - 1];
  int thrOff = waveOff + inc - s;
#pragma unroll
  for (int i = 0; i < SCAN_PER; i++) {
    int idx = base + i;
    if (idx < N_NODES) {
      int v = thrOff + local[i];
      offs[idx] = v;
      cursor[idx] = v;
    }
  }
  if (t == 0) offs[N_NODES] = ET;
}

__global__ void fill_kernel(const int* __restrict__ ei, int* __restrict__ cursor,
                            int* __restrict__ csr) {
  int e = blockIdx.x * blockDim.x + threadIdx.x;
  if (e >= ET) return;
  int src, dst;
  if (e < N_EDGES) { src = ei[e]; dst = ei[N_EDGES + e]; }
  else { src = e - N_EDGES; dst = src; }
  int pos = atomicAdd(&cursor[dst], 1);
  csr[pos] = src;
}

// ---------------- edge softmax L1: per (node,head) m,l + per-edge unnormalized p ----------------
__global__ __launch_bounds__(256) void esoft1_kernel(
    const float* __restrict__ as1, const float* __restrict__ ad1,
    const int* __restrict__ offs, const int* __restrict__ csr,
    float* __restrict__ pw, float* __restrict__ linv1) {
  int id = blockIdx.x * blockDim.x + threadIdx.x;
  if (id >= N_NODES * HEADS) return;
  int n = id >> 3, h = id & 7;
  int beg = offs[n], end = offs[n + 1];
  float ad = ad1[id];
  float m = -INFINITY;
  for (int k = beg; k < end; k++) {
    int src = csr[k];
    float e = as1[src * HEADS + h] + ad;
    e = (e > 0.f) ? e : NEG_SLOPE * e;
    m = fmaxf(m, e);
  }
  float l = 0.f;
  for (int k = beg; k < end; k++) {
    int src = csr[k];
    float e = as1[src * HEADS + h] + ad;
    e = (e > 0.f) ? e : NEG_SLOPE * e;
    float p = __expf(e - m);
    l += p;
    pw[(size_t)k * HEADS + h] = p;
  }
  linv1[id] = 1.f / (l + 1e-16f);
}

// ---------------- agg1: pure weighted gather (bf16 h1) + bias + ELU -> h2 ----------------
// 4 waves/block, one wave per node; lane covers 4 channels.
__global__ __launch_bounds__(256) void agg1_kernel(
    const unsigned short* __restrict__ h1b, const float* __restrict__ pw,
    const float* __restrict__ linv1, const int* __restrict__ offs,
    const int* __restrict__ csr, const float* __restrict__ b1,
    float* __restrict__ h2) {
  int n = blockIdx.x * 4 + (threadIdx.x >> 6);
  int lane = threadIdx.x & 63;
  int c4 = lane * 4;
  int head = lane >> 3;
  int beg = offs[n], end = offs[n + 1];
  float a0 = 0.f, a1 = 0.f, a2 = 0.f, a3 = 0.f;
  for (int k = beg; k < end; k++) {
    int src = csr[k];
    float p = pw[(size_t)k * HEADS + head];
    uint2 raw = *(const uint2*)(h1b + (size_t)src * HH + c4);
    a0 = fmaf(p, bf2f_lo(raw.x), a0);
    a1 = fmaf(p, bf2f_hi(raw.x), a1);
    a2 = fmaf(p, bf2f_lo(raw.y), a2);
    a3 = fmaf(p, bf2f_hi(raw.y), a3);
  }
  float li = linv1[n * HEADS + head];
  float4 bb = *(const float4*)(b1 + c4);
  float4 v = make_float4(a0 * li + bb.x, a1 * li + bb.y,
                         a2 * li + bb.z, a3 * li + bb.w);
  v.x = (v.x > 0.f) ? v.x : expm1f(v.x);
  v.y = (v.y > 0.f) ? v.y : expm1f(v.y);
  v.z = (v.z > 0.f) ? v.z : expm1f(v.z);
  v.w = (v.w > 0.f) ? v.w : expm1f(v.w);
  *(float4*)(h2 + (size_t)n * HH + c4) = v;
}

// ---------------- GEMM2: h3 = h2 @ w2 + b2   [20000,256]x[256,40] ----------------
__global__ __launch_bounds__(320) void gemm2_kernel(
    const float* __restrict__ h2, const float* __restrict__ w2,
    const float* __restrict__ b2, float* __restrict__ h3) {
  __shared__ float hs[32 * 257];
  __shared__ float ws2[HH * OUT_C];
  int t = threadIdx.x;
  int nodeBase = blockIdx.x * 32;
  const float* src = h2 + (size_t)nodeBase * HH;
  for (int idx = t; idx < 32 * 256; idx += 320) {
    int n = idx >> 8, k = idx & 255;
    hs[n * 257 + k] = src[idx];
  }
  for (int idx = t; idx < HH * OUT_C; idx += 320) ws2[idx] = w2[idx];
  __syncthreads();
  int c = t % OUT_C;
  int ng = t / OUT_C;
  float acc[4] = {0.f, 0.f, 0.f, 0.f};
  for (int k = 0; k < HH; k++) {
    float w = ws2[k * OUT_C + c];
#pragma unroll
    for (int i = 0; i < 4; i++) acc[i] += hs[(ng * 4 + i) * 257 + k] * w;
  }
  float bb = b2[c];
#pragma unroll
  for (int i = 0; i < 4; i++) {
    int n = nodeBase + ng * 4 + i;
    h3[(size_t)n * OUT_C + c] = acc[i] + bb;
  }
}

// ---------------- attn2 ----------------
__global__ __launch_bounds__(64) void attn2_kernel(
    const float* __restrict__ h3, const float* __restrict__ asrc,
    const float* __restrict__ adst, float* __restrict__ as2, float* __restrict__ ad2) {
  int n = blockIdx.x, t = threadIdx.x;
  float h = (t < OUT_C) ? h3[(size_t)n * OUT_C + t] : 0.f;
  float ps = (t < OUT_C) ? h * asrc[t] : 0.f;
  float pd = (t < OUT_C) ? h * adst[t] : 0.f;
  for (int o = 32; o > 0; o >>= 1) {
    ps += __shfl_down(ps, o, 64);
    pd += __shfl_down(pd, o, 64);
  }
  if (t == 0) { as2[n] = ps; ad2[n] = pd; }
}

// ---------------- edge softmax L2 ----------------
__global__ __launch_bounds__(256) void esoft2_kernel(
    const float* __restrict__ as2, const float* __restrict__ ad2,
    const int* __restrict__ offs, const int* __restrict__ csr,
    float* __restrict__ p2, float* __restrict__ linv2) {
  int n = blockIdx.x * blockDim.x + threadIdx.x;
  if (n >= N_NODES) return;
  int beg = offs[n], end = offs[n + 1];
  float ad = ad2[n];
  float m = -INFINITY;
  for (int k = beg; k < end; k++) {
    float e = as2[csr[k]] + ad;
    e = (e > 0.f) ? e : NEG_SLOPE * e;
    m = fmaxf(m, e);
  }
  float l = 0.f;
  for (int k = beg; k < end; k++) {
    float e = as2[csr[k]] + ad;
    e = (e > 0.f) ? e : NEG_SLOPE * e;
    float p = __expf(e - m);
    l += p;
    p2[k] = p;
  }
  linv2[n] = 1.f / (l + 1e-16f);
}

// ---------------- agg2: weighted gather + log_softmax -> out ----------------
// 4 waves/block, one wave per node; lanes 0..39 active channels.
__global__ __launch_bounds__(256) void agg2_kernel(
    const float* __restrict__ h3, const float* __restrict__ p2,
    const float* __restrict__ linv2, const int* __restrict__ offs,
    const int* __restrict__ csr, const float* __restrict__ b2,
    float* __restrict__ out) {
  int n = blockIdx.x * 4 + (threadIdx.x >> 6);
  int t = threadIdx.x & 63;
  bool act = (t < OUT_C);
  int beg = offs[n], end = offs[n + 1];
  float acc = 0.f;
  for (int k = beg; k < end; k++) {
    int src = csr[k];
    float p = p2[k];
    float hv = act ? h3[(size_t)src * OUT_C + t] : 0.f;
    acc = fmaf(p, hv, acc);
  }
  float v = acc * linv2[n] + (act ? b2[t] : 0.f);
  float x = act ? v : -INFINITY;
  float mx = x;
  for (int o = 32; o > 0; o >>= 1) mx = fmaxf(mx, __shfl_down(mx, o, 64));
  mx = __shfl(mx, 0, 64);
  float ex = act ? __expf(v - mx) : 0.f;
  float s = ex;
  for (int o = 32; o > 0; o >>= 1) s += __shfl_down(s, o, 64);
  s = __shfl(s, 0, 64);
  if (act) out[(size_t)n * OUT_C + t] = v - mx - logf(s);
}

extern "C" void kernel_launch(void* const* d_in, const int* in_sizes, int n_in,
                              void* d_out, int out_size, void* d_ws, size_t ws_size,
                              hipStream_t stream) {
  const float* x     = (const float*)d_in[0];
  const int*   ei    = (const int*)d_in[1];
  const float* w1    = (const float*)d_in[2];
  const float* asrc1 = (const float*)d_in[3];
  const float* adst1 = (const float*)d_in[4];
  const float* b1    = (const float*)d_in[5];
  const float* w2    = (const float*)d_in[6];
  const float* asrc2 = (const float*)d_in[7];
  const float* adst2 = (const float*)d_in[8];
  const float* b2    = (const float*)d_in[9];
  float* out = (float*)d_out;

  // workspace carve-up (~70 MB)
  float* fw = (float*)d_ws;
  float* as1   = fw;  fw += (size_t)N_NODES * HEADS;
  float* ad1   = fw;  fw += (size_t)N_NODES * HEADS;
  float* linv1 = fw;  fw += (size_t)N_NODES * HEADS;
  float* h2    = fw;  fw += (size_t)N_NODES * HH;
  float* h3    = fw;  fw += (size_t)N_NODES * OUT_C;
  float* as2   = fw;  fw += N_NODES;
  float* ad2   = fw;  fw += N_NODES;
  float* linv2 = fw;  fw += N_NODES;
  float* pw    = fw;  fw += (size_t)ET * HEADS;
  float* p2    = fw;  fw += (size_t)ET;
  unsigned short* h1b = (unsigned short*)fw;  fw += (size_t)N_NODES * HH / 2;
  unsigned short* xb  = (unsigned short*)fw;  fw += (size_t)N_NODES * IN_C / 2;
  unsigned short* wbT = (unsigned short*)fw;  fw += (size_t)IN_C * HH / 2;
  int* deg    = (int*)fw;
  int* offs   = deg + N_NODES;        // N+1
  int* cursor = offs + N_NODES + 1;
  int* csr    = cursor + N_NODES;     // ET

  hipMemsetAsync(deg, 0, N_NODES * sizeof(int), stream);

  convert_x_kernel<<<(N_NODES * IN_C / 4 + 255) / 256, 256, 0, stream>>>(x, xb);
  convert_w_kernel<<<(IN_C * HH + 255) / 256, 256, 0, stream>>>(w1, wbT);
  gemm1_kernel<<<dim3(HH / BN, (N_NODES + BM - 1) / BM), 256, 0, stream>>>(xb, wbT, b1, h1b, N_NODES);
  attn1_kernel<<<N_NODES, 256, 0, stream>>>(h1b, asrc1, adst1, as1, ad1);
  count_kernel<<<(ET + 255) / 256, 256, 0, stream>>>(ei, deg);
  scan_kernel<<<1, 1024, 0, stream>>>(deg, offs, cursor);
  fill_kernel<<<(ET + 255) / 256, 256, 0, stream>>>(ei, cursor, csr);
  esoft1_kernel<<<(N_NODES * HEADS + 255) / 256, 256, 0, stream>>>(as1, ad1, offs, csr, pw, linv1);
  agg1_kernel<<<N_NODES / 4, 256, 0, stream>>>(h1b, pw, linv1, offs, csr, b1, h2);
  gemm2_kernel<<<N_NODES / 32, 320, 0, stream>>>(h2, w2, b2, h3);
  attn2_kernel<<<N_NODES, 64, 0, stream>>>(h3, asrc2, adst2, as2, ad2);
  esoft2_kernel<<<(N_NODES + 255) / 256, 256, 0, stream>>>(as2, ad2, offs, csr, p2, linv2);
  agg2_kernel<<<N_NODES / 4, 256, 0, stream>>>(h3, p2, linv2, offs, csr, b2, out);
}

// Round 4
// 278.869 us; speedup vs baseline: 1.2402x; 1.2402x over previous
//
#include <hip/hip_runtime.h>
#include <hip/hip_bf16.h>
#include <math.h>

#define N_NODES 20000
#define N_EDGES 320000
#define ET (N_EDGES + N_NODES)   // with self loops = 340000
#define IN_C 512
#define HEADS 8
#define HID 32
#define HH (HEADS * HID)         // 256
#define OUT_C 40
#define NEG_SLOPE 0.2f

typedef __attribute__((ext_vector_type(8))) short short8;
typedef __attribute__((ext_vector_type(4))) float floatx4;

static __device__ __forceinline__ unsigned short f2bf(float f) {
  __hip_bfloat16 h = __float2bfloat16(f);
  return *(unsigned short*)&h;
}
static __device__ __forceinline__ float bf2f_lo(unsigned int u) {
  return __uint_as_float(u << 16);
}
static __device__ __forceinline__ float bf2f_hi(unsigned int u) {
  return __uint_as_float(u & 0xFFFF0000u);
}

// ---------------- convert x -> bf16  AND  w1 -> bf16 transposed ----------------
#define XCHUNKS (N_NODES * IN_C / 4)     // 2,560,000 float4 groups
__global__ __launch_bounds__(256) void convert_kernel(
    const float* __restrict__ x, const float* __restrict__ w1,
    unsigned short* __restrict__ xb, unsigned short* __restrict__ wbT) {
  int id = blockIdx.x * 256 + threadIdx.x;
  if (id < XCHUNKS) {
    size_t i = (size_t)id * 4;
    float4 v = *(const float4*)(x + i);
    ushort4 o;
    o.x = f2bf(v.x); o.y = f2bf(v.y); o.z = f2bf(v.z); o.w = f2bf(v.w);
    *(ushort4*)(xb + i) = o;
  } else {
    int j = id - XCHUNKS;
    if (j < IN_C * HH) {
      int k = j >> 8, n = j & 255;       // coalesced read of w1
      wbT[(size_t)n * IN_C + k] = f2bf(w1[j]);
    }
  }
}

// ---------------- GEMM1 (MFMA bf16): h1b = bf16(x @ w1 + b1) ----------------
// BM=64 rows, BN=128 cols -> grid.x = 2: A re-read only 2x (40 MB total)
#define BM 64
#define BN 128
#define BK 32
#define APAD 40   // row stride in shorts (80B)
__global__ __launch_bounds__(256) void gemm1_kernel(
    const unsigned short* __restrict__ A, const unsigned short* __restrict__ BT,
    const float* __restrict__ bias, unsigned short* __restrict__ C, int M) {
  __shared__ unsigned short As[BM][APAD];   // [64][40]
  __shared__ unsigned short Bs[BN][APAD];   // [128][40]
  const int tid = threadIdx.x;
  const int lane = tid & 63, wave = tid >> 6;
  const int wm = (wave & 1) * 32;
  const int wn = (wave >> 1) * 64;
  const int r16 = lane & 15, q = lane >> 4;
  const int rowBase = blockIdx.y * BM;
  const int colBase = blockIdx.x * BN;
  floatx4 acc[2][4] = {};

  for (int k0 = 0; k0 < IN_C; k0 += BK) {
    // stage A: 64 rows x 4 chunks = 256 -> 1 per thread
    {
      int row = tid >> 2, kc = (tid & 3) * 8;
      int arow = rowBase + row;
      float4 v = make_float4(0.f, 0.f, 0.f, 0.f);
      if (arow < M) v = *(const float4*)(A + (size_t)arow * IN_C + k0 + kc);
      *(float4*)&As[row][kc] = v;
    }
    // stage B: 128 rows x 4 chunks = 512 -> 2 per thread
#pragma unroll
    for (int i = 0; i < 2; i++) {
      int c = tid + i * 256;
      int row = c >> 2, kc = (c & 3) * 8;
      float4 v = *(const float4*)(BT + (size_t)(colBase + row) * IN_C + k0 + kc);
      *(float4*)&Bs[row][kc] = v;
    }
    __syncthreads();
    short8 afrag[2], bfrag[4];
#pragma unroll
    for (int mt = 0; mt < 2; mt++)
      afrag[mt] = *(const short8*)&As[wm + mt * 16 + r16][q * 8];
#pragma unroll
    for (int nt = 0; nt < 4; nt++)
      bfrag[nt] = *(const short8*)&Bs[wn + nt * 16 + r16][q * 8];
#pragma unroll
    for (int mt = 0; mt < 2; mt++)
#pragma unroll
      for (int nt = 0; nt < 4; nt++)
        acc[mt][nt] = __builtin_amdgcn_mfma_f32_16x16x32_bf16(
            afrag[mt], bfrag[nt], acc[mt][nt], 0, 0, 0);
    __syncthreads();
  }
#pragma unroll
  for (int mt = 0; mt < 2; mt++) {
#pragma unroll
    for (int nt = 0; nt < 4; nt++) {
      int col = colBase + wn + nt * 16 + r16;
      float bb = bias[col];
#pragma unroll
      for (int r = 0; r < 4; r++) {
        int row = rowBase + wm + mt * 16 + q * 4 + r;
        if (row < M) C[(size_t)row * HH + col] = f2bf(acc[mt][nt][r] + bb);
      }
    }
  }
}

// ---------------- attn1: per-node per-head dot with att vectors (bf16 h1) ----------------
__global__ __launch_bounds__(256) void attn1_kernel(
    const unsigned short* __restrict__ h1b, const float* __restrict__ asrc,
    const float* __restrict__ adst, float* __restrict__ as1, float* __restrict__ ad1) {
  int n = blockIdx.x, t = threadIdx.x;       // t = head*32 + c
  float h = bf2f_lo((unsigned int)h1b[(size_t)n * HH + t]);
  float ps = h * asrc[t];
  float pd = h * adst[t];
  for (int o = 16; o > 0; o >>= 1) {
    ps += __shfl_down(ps, o, 32);
    pd += __shfl_down(pd, o, 32);
  }
  if ((t & 31) == 0) {
    as1[n * HEADS + (t >> 5)] = ps;
    ad1[n * HEADS + (t >> 5)] = pd;
  }
}

// ---------------- CSR build (by dst) ----------------
__global__ void count_kernel(const int* __restrict__ ei, int* __restrict__ deg) {
  int e = blockIdx.x * blockDim.x + threadIdx.x;
  if (e >= ET) return;
  int dst = (e < N_EDGES) ? ei[N_EDGES + e] : (e - N_EDGES);
  atomicAdd(&deg[dst], 1);
}

#define SCAN_PER 20
__global__ __launch_bounds__(1024) void scan_kernel(
    const int* __restrict__ deg, int* __restrict__ offs, int* __restrict__ cursor) {
  __shared__ int wsum[16];
  int t = threadIdx.x;
  int base = t * SCAN_PER;
  int local[SCAN_PER];
  int s = 0;
#pragma unroll
  for (int i = 0; i < SCAN_PER; i++) {
    int idx = base + i;
    int v = (idx < N_NODES) ? deg[idx] : 0;
    local[i] = s;
    s += v;
  }
  int lane = t & 63, w = t >> 6;
  int inc = s;
  for (int o = 1; o < 64; o <<= 1) {
    int u = __shfl_up(inc, o, 64);
    if (lane >= o) inc += u;
  }
  if (lane == 63) wsum[w] = inc;
  __syncthreads();
  if (w == 0 && lane < 16) {
    int v = wsum[lane];
    for (int o = 1; o < 16; o <<= 1) {
      int u = __shfl_up(v, o, 64);
      if (lane >= o) v += u;
    }
    wsum[lane] = v;
  }
  __syncthreads();
  int waveOff = (w == 0) ? 0 : wsum[w - 1];
  int thrOff = waveOff + inc - s;
#pragma unroll
  for (int i = 0; i < SCAN_PER; i++) {
    int idx = base + i;
    if (idx < N_NODES) {
      int v = thrOff + local[i];
      offs[idx] = v;
      cursor[idx] = v;
    }
  }
  if (t == 0) offs[N_NODES] = ET;
}

__global__ void fill_kernel(const int* __restrict__ ei, int* __restrict__ cursor,
                            int* __restrict__ csr) {
  int e = blockIdx.x * blockDim.x + threadIdx.x;
  if (e >= ET) return;
  int src, dst;
  if (e < N_EDGES) { src = ei[e]; dst = ei[N_EDGES + e]; }
  else { src = e - N_EDGES; dst = src; }
  int pos = atomicAdd(&cursor[dst], 1);
  csr[pos] = src;
}

// ---------------- agg1 (fused max-free softmax + gather + bias + ELU) ----------------
// 4 waves/block, one wave per node. Wave splits: half=lane>>5 covers even/odd
// edges; each half-lane covers 8 channels (16B bf16 load). 2 edge-rows in
// flight per load instruction; final shfl_xor(32) combines halves.
__global__ __launch_bounds__(256) void agg1_kernel(
    const unsigned short* __restrict__ h1b, const float* __restrict__ as1,
    const float* __restrict__ ad1, const int* __restrict__ offs,
    const int* __restrict__ csr, const float* __restrict__ b1,
    float* __restrict__ h2) {
  int n = blockIdx.x * 4 + (threadIdx.x >> 6);
  int lane = threadIdx.x & 63;
  int half = lane >> 5;
  int sl = lane & 31;
  int c8 = sl * 8;
  int head = sl >> 2;
  int beg = offs[n], end = offs[n + 1];
  float ad = ad1[n * HEADS + head];
  float acc[8] = {};
  float l = 0.f;
#pragma unroll 2
  for (int k = beg + half; k < end; k += 2) {
    int src = csr[k];
    float e = as1[src * HEADS + head] + ad;
    e = (e > 0.f) ? e : NEG_SLOPE * e;
    float p = __expf(e);
    l += p;
    uint4 raw = *(const uint4*)(h1b + (size_t)src * HH + c8);
    acc[0] = fmaf(p, bf2f_lo(raw.x), acc[0]);
    acc[1] = fmaf(p, bf2f_hi(raw.x), acc[1]);
    acc[2] = fmaf(p, bf2f_lo(raw.y), acc[2]);
    acc[3] = fmaf(p, bf2f_hi(raw.y), acc[3]);
    acc[4] = fmaf(p, bf2f_lo(raw.z), acc[4]);
    acc[5] = fmaf(p, bf2f_hi(raw.z), acc[5]);
    acc[6] = fmaf(p, bf2f_lo(raw.w), acc[6]);
    acc[7] = fmaf(p, bf2f_hi(raw.w), acc[7]);
  }
#pragma unroll
  for (int j = 0; j < 8; j++) acc[j] += __shfl_xor(acc[j], 32, 64);
  l += __shfl_xor(l, 32, 64);
  if (half == 0) {
    float li = 1.f / (l + 1e-16f);
    float4 b0 = *(const float4*)(b1 + c8);
    float4 b4 = *(const float4*)(b1 + c8 + 4);
    float v[8];
    v[0] = acc[0] * li + b0.x; v[1] = acc[1] * li + b0.y;
    v[2] = acc[2] * li + b0.z; v[3] = acc[3] * li + b0.w;
    v[4] = acc[4] * li + b4.x; v[5] = acc[5] * li + b4.y;
    v[6] = acc[6] * li + b4.z; v[7] = acc[7] * li + b4.w;
#pragma unroll
    for (int j = 0; j < 8; j++) v[j] = (v[j] > 0.f) ? v[j] : expm1f(v[j]);
    *(float4*)(h2 + (size_t)n * HH + c8) = make_float4(v[0], v[1], v[2], v[3]);
    *(float4*)(h2 + (size_t)n * HH + c8 + 4) = make_float4(v[4], v[5], v[6], v[7]);
  }
}

// ---------------- GEMM2 + attn2 fused: h3 = h2 @ w2 + b2; as2/ad2 dots ----------------
__global__ __launch_bounds__(320) void gemm2_kernel(
    const float* __restrict__ h2, const float* __restrict__ w2,
    const float* __restrict__ b2, const float* __restrict__ asrc2,
    const float* __restrict__ adst2, float* __restrict__ h3,
    float* __restrict__ as2, float* __restrict__ ad2) {
  __shared__ float hs[32 * 257];
  __shared__ float ws2[HH * OUT_C];
  int t = threadIdx.x;
  int nodeBase = blockIdx.x * 32;
  const float* src = h2 + (size_t)nodeBase * HH;
  for (int idx = t; idx < 32 * 256; idx += 320) {
    int n = idx >> 8, k = idx & 255;
    hs[n * 257 + k] = src[idx];
  }
  for (int idx = t; idx < HH * OUT_C; idx += 320) ws2[idx] = w2[idx];
  __syncthreads();
  int c = t % OUT_C;
  int ng = t / OUT_C;
  float acc[4] = {0.f, 0.f, 0.f, 0.f};
  for (int k = 0; k < HH; k++) {
    float w = ws2[k * OUT_C + c];
#pragma unroll
    for (int i = 0; i < 4; i++) acc[i] += hs[(ng * 4 + i) * 257 + k] * w;
  }
  float bb = b2[c];
  float sa = asrc2[c], sd = adst2[c];
  float v[4];
#pragma unroll
  for (int i = 0; i < 4; i++) {
    v[i] = acc[i] + bb;
    h3[(size_t)(nodeBase + ng * 4 + i) * OUT_C + c] = v[i];
  }
  __syncthreads();                  // all hs reads done; safe to reuse
  float* sp = hs;                   // [40][32]
  float* sd2 = hs + OUT_C * 32;     // [40][32]
#pragma unroll
  for (int i = 0; i < 4; i++) {
    sp[c * 32 + ng * 4 + i] = v[i] * sa;
    sd2[c * 32 + ng * 4 + i] = v[i] * sd;
  }
  __syncthreads();
  if (t < 32) {
    float ss = 0.f, dd = 0.f;
    for (int cc = 0; cc < OUT_C; cc++) {
      ss += sp[cc * 32 + t];
      dd += sd2[cc * 32 + t];
    }
    as2[nodeBase + t] = ss;
    ad2[nodeBase + t] = dd;
  }
}

// ---------------- agg2 (fused max-free softmax + gather) + log_softmax -> out ----------------
__global__ __launch_bounds__(256) void agg2_kernel(
    const float* __restrict__ h3, const float* __restrict__ as2,
    const float* __restrict__ ad2, const int* __restrict__ offs,
    const int* __restrict__ csr, const float* __restrict__ b2,
    float* __restrict__ out) {
  int n = blockIdx.x * 4 + (threadIdx.x >> 6);
  int t = threadIdx.x & 63;
  bool act = (t < OUT_C);
  int beg = offs[n], end = offs[n + 1];
  float ad = ad2[n];
  float l = 0.f, acc = 0.f;
#pragma unroll 2
  for (int k = beg; k < end; k++) {
    int src = csr[k];
    float e = as2[src] + ad;
    e = (e > 0.f) ? e : NEG_SLOPE * e;
    float p = __expf(e);
    l += p;
    float hv = act ? h3[(size_t)src * OUT_C + t] : 0.f;
    acc = fmaf(p, hv, acc);
  }
  float v = acc / (l + 1e-16f) + (act ? b2[t] : 0.f);
  float x = act ? v : -INFINITY;
  float mx = x;
  for (int o = 32; o > 0; o >>= 1) mx = fmaxf(mx, __shfl_down(mx, o, 64));
  mx = __shfl(mx, 0, 64);
  float ex = act ? __expf(v - mx) : 0.f;
  float s = ex;
  for (int o = 32; o > 0; o >>= 1) s += __shfl_down(s, o, 64);
  s = __shfl(s, 0, 64);
  if (act) out[(size_t)n * OUT_C + t] = v - mx - logf(s);
}

extern "C" void kernel_launch(void* const* d_in, const int* in_sizes, int n_in,
                              void* d_out, int out_size, void* d_ws, size_t ws_size,
                              hipStream_t stream) {
  const float* x     = (const float*)d_in[0];
  const int*   ei    = (const int*)d_in[1];
  const float* w1    = (const float*)d_in[2];
  const float* asrc1 = (const float*)d_in[3];
  const float* adst1 = (const float*)d_in[4];
  const float* b1    = (const float*)d_in[5];
  const float* w2    = (const float*)d_in[6];
  const float* asrc2 = (const float*)d_in[7];
  const float* adst2 = (const float*)d_in[8];
  const float* b2    = (const float*)d_in[9];
  float* out = (float*)d_out;

  // workspace carve-up
  float* fw = (float*)d_ws;
  float* as1   = fw;  fw += (size_t)N_NODES * HEADS;
  float* ad1   = fw;  fw += (size_t)N_NODES * HEADS;
  float* h2    = fw;  fw += (size_t)N_NODES * HH;
  float* h3    = fw;  fw += (size_t)N_NODES * OUT_C;
  float* as2   = fw;  fw += N_NODES;
  float* ad2   = fw;  fw += N_NODES;
  unsigned short* h1b = (unsigned short*)fw;  fw += (size_t)N_NODES * HH / 2;
  unsigned short* xb  = (unsigned short*)fw;  fw += (size_t)N_NODES * IN_C / 2;
  unsigned short* wbT = (unsigned short*)fw;  fw += (size_t)IN_C * HH / 2;
  int* deg    = (int*)fw;
  int* offs   = deg + N_NODES;        // N+1
  int* cursor = offs + N_NODES + 1;
  int* csr    = cursor + N_NODES;     // ET

  hipMemsetAsync(deg, 0, N_NODES * sizeof(int), stream);

  convert_kernel<<<(XCHUNKS + IN_C * HH + 255) / 256, 256, 0, stream>>>(x, w1, xb, wbT);
  gemm1_kernel<<<dim3(HH / BN, (N_NODES + BM - 1) / BM), 256, 0, stream>>>(xb, wbT, b1, h1b, N_NODES);
  attn1_kernel<<<N_NODES, 256, 0, stream>>>(h1b, asrc1, adst1, as1, ad1);
  count_kernel<<<(ET + 255) / 256, 256, 0, stream>>>(ei, deg);
  scan_kernel<<<1, 1024, 0, stream>>>(deg, offs, cursor);
  fill_kernel<<<(ET + 255) / 256, 256, 0, stream>>>(ei, cursor, csr);
  agg1_kernel<<<N_NODES / 4, 256, 0, stream>>>(h1b, as1, ad1, offs, csr, b1, h2);
  gemm2_kernel<<<N_NODES / 32, 320, 0, stream>>>(h2, w2, b2, asrc2, adst2, h3, as2, ad2);
  agg2_kernel<<<N_NODES / 4, 256, 0, stream>>>(h3, as2, ad2, offs, csr, b2, out);
}

// Round 5
// 277.656 us; speedup vs baseline: 1.2456x; 1.0044x over previous
//
#include <hip/hip_runtime.h>
#include <hip/hip_bf16.h>
#include <math.h>

#define N_NODES 20000
#define N_EDGES 320000
#define ET (N_EDGES + N_NODES)   // with self loops = 340000
#define IN_C 512
#define HEADS 8
#define HID 32
#define HH (HEADS * HID)         // 256
#define OUT_C 40
#define NEG_SLOPE 0.2f

typedef __attribute__((ext_vector_type(8))) short short8;
typedef __attribute__((ext_vector_type(4))) float floatx4;

static __device__ __forceinline__ unsigned short f2bf(float f) {
  __hip_bfloat16 h = __float2bfloat16(f);
  return *(unsigned short*)&h;
}
static __device__ __forceinline__ float bf2f_lo(unsigned int u) {
  return __uint_as_float(u << 16);
}
static __device__ __forceinline__ float bf2f_hi(unsigned int u) {
  return __uint_as_float(u & 0xFFFF0000u);
}

// ================= L1: w1 -> bf16 transposed  +  edge count =================
#define WCONV_BLOCKS (IN_C * HH / 256)          // 512
#define COUNT_BLOCKS ((ET + 255) / 256)         // 1329
__global__ __launch_bounds__(256) void prep_kernel(
    const float* __restrict__ w1, const int* __restrict__ ei,
    unsigned short* __restrict__ wbT, int* __restrict__ deg) {
  if (blockIdx.x < WCONV_BLOCKS) {
    int j = blockIdx.x * 256 + threadIdx.x;     // coalesced read of w1
    int k = j >> 8, n = j & 255;
    wbT[(size_t)n * IN_C + k] = f2bf(w1[j]);
  } else {
    int e = (blockIdx.x - WCONV_BLOCKS) * 256 + threadIdx.x;
    if (e < ET) {
      int dst = (e < N_EDGES) ? ei[N_EDGES + e] : (e - N_EDGES);
      atomicAdd(&deg[dst], 1);
    }
  }
}

// ================= L2: GEMM1 (MFMA bf16, f32 A staged+converted) + CSR scan ==
// h1b = bf16(x @ w1 + b1); BM=64, BN=128; grid = 2*313 gemm blocks + 1 scan.
#define BM 64
#define BN 128
#define BK 32
#define APAD 40   // row stride in shorts (80B)
#define GY ((N_NODES + BM - 1) / BM)            // 313
#define GEMM_BLOCKS (2 * GY)                    // 626
#define SCAN_PER 79                             // 256*79 >= 20000
__global__ __launch_bounds__(256) void gemm1_kernel(
    const float* __restrict__ X, const unsigned short* __restrict__ BT,
    const float* __restrict__ bias, unsigned short* __restrict__ C,
    const int* __restrict__ deg, int* __restrict__ offs, int* __restrict__ cursor) {
  if (blockIdx.x >= GEMM_BLOCKS) {
    // ---- CSR exclusive scan over deg (one 256-thread block) ----
    __shared__ int wsum[4];
    int t = threadIdx.x;
    int base = t * SCAN_PER;
    int s = 0;
    for (int i = 0; i < SCAN_PER; i++) {
      int idx = base + i;
      s += (idx < N_NODES) ? deg[idx] : 0;
    }
    int lane = t & 63, w = t >> 6;
    int inc = s;
    for (int o = 1; o < 64; o <<= 1) {
      int u = __shfl_up(inc, o, 64);
      if (lane >= o) inc += u;
    }
    if (lane == 63) wsum[w] = inc;
    __syncthreads();
    int waveOff = 0;
    for (int i = 0; i < w; i++) waveOff += wsum[i];
    int running = waveOff + inc - s;
    for (int i = 0; i < SCAN_PER; i++) {
      int idx = base + i;
      if (idx < N_NODES) {
        offs[idx] = running;
        cursor[idx] = running;
        running += deg[idx];
      }
    }
    if (t == 0) offs[N_NODES] = ET;
    return;
  }
  // ---- GEMM tile ----
  __shared__ unsigned short As[BM][APAD];   // [64][40]
  __shared__ unsigned short Bs[BN][APAD];   // [128][40]
  const int tid = threadIdx.x;
  const int lane = tid & 63, wave = tid >> 6;
  const int wm = (wave & 1) * 32;
  const int wn = (wave >> 1) * 64;
  const int r16 = lane & 15, q = lane >> 4;
  const int bx = blockIdx.x & 1, by = blockIdx.x >> 1;
  const int rowBase = by * BM;
  const int colBase = bx * BN;
  floatx4 acc[2][4] = {};

  for (int k0 = 0; k0 < IN_C; k0 += BK) {
    // stage A from f32 x, converting to bf16: 64 rows x 32 k
    {
      int row = tid >> 2, kc = (tid & 3) * 8;
      int arow = rowBase + row;
      float4 v0 = make_float4(0.f, 0.f, 0.f, 0.f), v1 = v0;
      if (arow < N_NODES) {
        const float* p = X + (size_t)arow * IN_C + k0 + kc;
        v0 = *(const float4*)p;
        v1 = *(const float4*)(p + 4);
      }
      unsigned short tmp[8] = {f2bf(v0.x), f2bf(v0.y), f2bf(v0.z), f2bf(v0.w),
                               f2bf(v1.x), f2bf(v1.y), f2bf(v1.z), f2bf(v1.w)};
      *(float4*)&As[row][kc] = *(const float4*)tmp;
    }
    // stage B (bf16): 128 rows x 32 k -> 2 chunks per thread
#pragma unroll
    for (int i = 0; i < 2; i++) {
      int c = tid + i * 256;
      int row = c >> 2, kc = (c & 3) * 8;
      float4 v = *(const float4*)(BT + (size_t)(colBase + row) * IN_C + k0 + kc);
      *(float4*)&Bs[row][kc] = v;
    }
    __syncthreads();
    short8 afrag[2], bfrag[4];
#pragma unroll
    for (int mt = 0; mt < 2; mt++)
      afrag[mt] = *(const short8*)&As[wm + mt * 16 + r16][q * 8];
#pragma unroll
    for (int nt = 0; nt < 4; nt++)
      bfrag[nt] = *(const short8*)&Bs[wn + nt * 16 + r16][q * 8];
#pragma unroll
    for (int mt = 0; mt < 2; mt++)
#pragma unroll
      for (int nt = 0; nt < 4; nt++)
        acc[mt][nt] = __builtin_amdgcn_mfma_f32_16x16x32_bf16(
            afrag[mt], bfrag[nt], acc[mt][nt], 0, 0, 0);
    __syncthreads();
  }
#pragma unroll
  for (int mt = 0; mt < 2; mt++) {
#pragma unroll
    for (int nt = 0; nt < 4; nt++) {
      int col = colBase + wn + nt * 16 + r16;
      float bb = bias[col];
#pragma unroll
      for (int r = 0; r < 4; r++) {
        int row = rowBase + wm + mt * 16 + q * 4 + r;
        if (row < N_NODES) C[(size_t)row * HH + col] = f2bf(acc[mt][nt][r] + bb);
      }
    }
  }
}

// ================= L3: CSR fill + attn1 (wave-per-node dots) =================
#define FILL_BLOCKS ((ET + 255) / 256)          // 1329
#define ATTN1_BLOCKS (N_NODES / 4)              // 5000
__global__ __launch_bounds__(256) void fill_attn1_kernel(
    const int* __restrict__ ei, int* __restrict__ cursor, int* __restrict__ csr,
    const unsigned short* __restrict__ h1b, const float* __restrict__ asrc,
    const float* __restrict__ adst, float* __restrict__ as1, float* __restrict__ ad1) {
  if (blockIdx.x < FILL_BLOCKS) {
    int e = blockIdx.x * 256 + threadIdx.x;
    if (e >= ET) return;
    int src, dst;
    if (e < N_EDGES) { src = ei[e]; dst = ei[N_EDGES + e]; }
    else { src = e - N_EDGES; dst = src; }
    int pos = atomicAdd(&cursor[dst], 1);
    csr[pos] = src;
  } else {
    int wave = threadIdx.x >> 6, lane = threadIdx.x & 63;
    int n = (blockIdx.x - FILL_BLOCKS) * 4 + wave;   // exact: 5000*4 = 20000
    int c4 = lane * 4;
    uint2 raw = *(const uint2*)(h1b + (size_t)n * HH + c4);
    float h0 = bf2f_lo(raw.x), h1 = bf2f_hi(raw.x);
    float h2 = bf2f_lo(raw.y), h3 = bf2f_hi(raw.y);
    float4 sa = *(const float4*)(asrc + c4);
    float4 sd = *(const float4*)(adst + c4);
    float ps = h0 * sa.x + h1 * sa.y + h2 * sa.z + h3 * sa.w;
    float pd = h0 * sd.x + h1 * sd.y + h2 * sd.z + h3 * sd.w;
#pragma unroll
    for (int o = 4; o > 0; o >>= 1) {
      ps += __shfl_down(ps, o, 8);
      pd += __shfl_down(pd, o, 8);
    }
    if ((lane & 7) == 0) {
      as1[n * HEADS + (lane >> 3)] = ps;
      ad1[n * HEADS + (lane >> 3)] = pd;
    }
  }
}

// ================= L4: agg1 (max-free softmax + gather + bias + ELU) =========
__global__ __launch_bounds__(256) void agg1_kernel(
    const unsigned short* __restrict__ h1b, const float* __restrict__ as1,
    const float* __restrict__ ad1, const int* __restrict__ offs,
    const int* __restrict__ csr, const float* __restrict__ b1,
    float* __restrict__ h2) {
  int n = blockIdx.x * 4 + (threadIdx.x >> 6);
  int lane = threadIdx.x & 63;
  int half = lane >> 5;
  int sl = lane & 31;
  int c8 = sl * 8;
  int head = sl >> 2;
  int beg = offs[n], end = offs[n + 1];
  float ad = ad1[n * HEADS + head];
  float acc[8] = {};
  float l = 0.f;
#pragma unroll 2
  for (int k = beg + half; k < end; k += 2) {
    int src = csr[k];
    float e = as1[src * HEADS + head] + ad;
    e = (e > 0.f) ? e : NEG_SLOPE * e;
    float p = __expf(e);
    l += p;
    uint4 raw = *(const uint4*)(h1b + (size_t)src * HH + c8);
    acc[0] = fmaf(p, bf2f_lo(raw.x), acc[0]);
    acc[1] = fmaf(p, bf2f_hi(raw.x), acc[1]);
    acc[2] = fmaf(p, bf2f_lo(raw.y), acc[2]);
    acc[3] = fmaf(p, bf2f_hi(raw.y), acc[3]);
    acc[4] = fmaf(p, bf2f_lo(raw.z), acc[4]);
    acc[5] = fmaf(p, bf2f_hi(raw.z), acc[5]);
    acc[6] = fmaf(p, bf2f_lo(raw.w), acc[6]);
    acc[7] = fmaf(p, bf2f_hi(raw.w), acc[7]);
  }
#pragma unroll
  for (int j = 0; j < 8; j++) acc[j] += __shfl_xor(acc[j], 32, 64);
  l += __shfl_xor(l, 32, 64);
  if (half == 0) {
    float li = 1.f / (l + 1e-16f);
    float4 b0 = *(const float4*)(b1 + c8);
    float4 b4 = *(const float4*)(b1 + c8 + 4);
    float v[8];
    v[0] = acc[0] * li + b0.x; v[1] = acc[1] * li + b0.y;
    v[2] = acc[2] * li + b0.z; v[3] = acc[3] * li + b0.w;
    v[4] = acc[4] * li + b4.x; v[5] = acc[5] * li + b4.y;
    v[6] = acc[6] * li + b4.z; v[7] = acc[7] * li + b4.w;
#pragma unroll
    for (int j = 0; j < 8; j++) v[j] = (v[j] > 0.f) ? v[j] : expm1f(v[j]);
    *(float4*)(h2 + (size_t)n * HH + c8) = make_float4(v[0], v[1], v[2], v[3]);
    *(float4*)(h2 + (size_t)n * HH + c8 + 4) = make_float4(v[4], v[5], v[6], v[7]);
  }
}

// ================= L5: GEMM2 + attn2 fused ===================================
__global__ __launch_bounds__(320) void gemm2_kernel(
    const float* __restrict__ h2, const float* __restrict__ w2,
    const float* __restrict__ b2, const float* __restrict__ asrc2,
    const float* __restrict__ adst2, float* __restrict__ h3,
    float* __restrict__ as2, float* __restrict__ ad2) {
  __shared__ float hs[32 * 257];
  __shared__ float ws2[HH * OUT_C];
  int t = threadIdx.x;
  int nodeBase = blockIdx.x * 32;
  const float* src = h2 + (size_t)nodeBase * HH;
  for (int idx = t; idx < 32 * 256; idx += 320) {
    int n = idx >> 8, k = idx & 255;
    hs[n * 257 + k] = src[idx];
  }
  for (int idx = t; idx < HH * OUT_C; idx += 320) ws2[idx] = w2[idx];
  __syncthreads();
  int c = t % OUT_C;
  int ng = t / OUT_C;
  float acc[4] = {0.f, 0.f, 0.f, 0.f};
  for (int k = 0; k < HH; k++) {
    float w = ws2[k * OUT_C + c];
#pragma unroll
    for (int i = 0; i < 4; i++) acc[i] += hs[(ng * 4 + i) * 257 + k] * w;
  }
  float bb = b2[c];
  float sa = asrc2[c], sd = adst2[c];
  float v[4];
#pragma unroll
  for (int i = 0; i < 4; i++) {
    v[i] = acc[i] + bb;
    h3[(size_t)(nodeBase + ng * 4 + i) * OUT_C + c] = v[i];
  }
  __syncthreads();                  // all hs reads done; safe to reuse
  float* sp = hs;                   // [40][32]
  float* sd2 = hs + OUT_C * 32;     // [40][32]
#pragma unroll
  for (int i = 0; i < 4; i++) {
    sp[c * 32 + ng * 4 + i] = v[i] * sa;
    sd2[c * 32 + ng * 4 + i] = v[i] * sd;
  }
  __syncthreads();
  if (t < 32) {
    float ss = 0.f, dd = 0.f;
    for (int cc = 0; cc < OUT_C; cc++) {
      ss += sp[cc * 32 + t];
      dd += sd2[cc * 32 + t];
    }
    as2[nodeBase + t] = ss;
    ad2[nodeBase + t] = dd;
  }
}

// ================= L6: agg2 (max-free softmax + gather) + log_softmax ========
__global__ __launch_bounds__(256) void agg2_kernel(
    const float* __restrict__ h3, const float* __restrict__ as2,
    const float* __restrict__ ad2, const int* __restrict__ offs,
    const int* __restrict__ csr, const float* __restrict__ b2,
    float* __restrict__ out) {
  int n = blockIdx.x * 4 + (threadIdx.x >> 6);
  int t = threadIdx.x & 63;
  bool act = (t < OUT_C);
  int beg = offs[n], end = offs[n + 1];
  float ad = ad2[n];
  float l = 0.f, acc = 0.f;
#pragma unroll 2
  for (int k = beg; k < end; k++) {
    int src = csr[k];
    float e = as2[src] + ad;
    e = (e > 0.f) ? e : NEG_SLOPE * e;
    float p = __expf(e);
    l += p;
    float hv = act ? h3[(size_t)src * OUT_C + t] : 0.f;
    acc = fmaf(p, hv, acc);
  }
  float v = acc / (l + 1e-16f) + (act ? b2[t] : 0.f);
  float x = act ? v : -INFINITY;
  float mx = x;
  for (int o = 32; o > 0; o >>= 1) mx = fmaxf(mx, __shfl_down(mx, o, 64));
  mx = __shfl(mx, 0, 64);
  float ex = act ? __expf(v - mx) : 0.f;
  float s = ex;
  for (int o = 32; o > 0; o >>= 1) s += __shfl_down(s, o, 64);
  s = __shfl(s, 0, 64);
  if (act) out[(size_t)n * OUT_C + t] = v - mx - logf(s);
}

extern "C" void kernel_launch(void* const* d_in, const int* in_sizes, int n_in,
                              void* d_out, int out_size, void* d_ws, size_t ws_size,
                              hipStream_t stream) {
  const float* x     = (const float*)d_in[0];
  const int*   ei    = (const int*)d_in[1];
  const float* w1    = (const float*)d_in[2];
  const float* asrc1 = (const float*)d_in[3];
  const float* adst1 = (const float*)d_in[4];
  const float* b1    = (const float*)d_in[5];
  const float* w2    = (const float*)d_in[6];
  const float* asrc2 = (const float*)d_in[7];
  const float* adst2 = (const float*)d_in[8];
  const float* b2    = (const float*)d_in[9];
  float* out = (float*)d_out;

  // workspace carve-up (~37 MB)
  float* fw = (float*)d_ws;
  float* as1   = fw;  fw += (size_t)N_NODES * HEADS;
  float* ad1   = fw;  fw += (size_t)N_NODES * HEADS;
  float* h2    = fw;  fw += (size_t)N_NODES * HH;
  float* h3    = fw;  fw += (size_t)N_NODES * OUT_C;
  float* as2   = fw;  fw += N_NODES;
  float* ad2   = fw;  fw += N_NODES;
  unsigned short* h1b = (unsigned short*)fw;  fw += (size_t)N_NODES * HH / 2;
  unsigned short* wbT = (unsigned short*)fw;  fw += (size_t)IN_C * HH / 2;
  int* deg    = (int*)fw;
  int* offs   = deg + N_NODES;        // N+1
  int* cursor = offs + N_NODES + 1;
  int* csr    = cursor + N_NODES;     // ET

  hipMemsetAsync(deg, 0, N_NODES * sizeof(int), stream);

  prep_kernel<<<WCONV_BLOCKS + COUNT_BLOCKS, 256, 0, stream>>>(w1, ei, wbT, deg);
  gemm1_kernel<<<GEMM_BLOCKS + 1, 256, 0, stream>>>(x, wbT, b1, h1b, deg, offs, cursor);
  fill_attn1_kernel<<<FILL_BLOCKS + ATTN1_BLOCKS, 256, 0, stream>>>(
      ei, cursor, csr, h1b, asrc1, adst1, as1, ad1);
  agg1_kernel<<<N_NODES / 4, 256, 0, stream>>>(h1b, as1, ad1, offs, csr, b1, h2);
  gemm2_kernel<<<N_NODES / 32, 320, 0, stream>>>(h2, w2, b2, asrc2, adst2, h3, as2, ad2);
  agg2_kernel<<<N_NODES / 4, 256, 0, stream>>>(h3, as2, ad2, offs, csr, b2, out);
}

// Round 6
// 242.721 us; speedup vs baseline: 1.4249x; 1.1439x over previous
//
#include <hip/hip_runtime.h>
#include <hip/hip_bf16.h>
#include <math.h>

#define N_NODES 20000
#define N_EDGES 320000
#define ET (N_EDGES + N_NODES)   // with self loops = 340000
#define IN_C 512
#define HEADS 8
#define HID 32
#define HH (HEADS * HID)         // 256
#define OUT_C 40
#define NEG_SLOPE 0.2f

typedef __attribute__((ext_vector_type(8))) short short8;
typedef __attribute__((ext_vector_type(4))) float floatx4;

static __device__ __forceinline__ unsigned short f2bf(float f) {
  __hip_bfloat16 h = __float2bfloat16(f);
  return *(unsigned short*)&h;
}
static __device__ __forceinline__ float bf2f_lo(unsigned int u) {
  return __uint_as_float(u << 16);
}
static __device__ __forceinline__ float bf2f_hi(unsigned int u) {
  return __uint_as_float(u & 0xFFFF0000u);
}

// ================= L1: w1 -> bf16 transposed  +  edge count =================
#define WCONV_BLOCKS (IN_C * HH / 256)          // 512
#define COUNT_BLOCKS ((ET + 255) / 256)         // 1329
__global__ __launch_bounds__(256) void prep_kernel(
    const float* __restrict__ w1, const int* __restrict__ ei,
    unsigned short* __restrict__ wbT, int* __restrict__ deg) {
  if (blockIdx.x < WCONV_BLOCKS) {
    int j = blockIdx.x * 256 + threadIdx.x;     // coalesced read of w1
    int k = j >> 8, n = j & 255;
    wbT[(size_t)n * IN_C + k] = f2bf(w1[j]);
  } else {
    int e = (blockIdx.x - WCONV_BLOCKS) * 256 + threadIdx.x;
    if (e < ET) {
      int dst = (e < N_EDGES) ? ei[N_EDGES + e] : (e - N_EDGES);
      atomicAdd(&deg[dst], 1);
    }
  }
}

// ================= L2: GEMM1 (MFMA bf16, f32 A staged+converted) + CSR scan ==
// h1b = bf16(x @ w1 + b1); BM=64, BN=128; grid = 2*313 gemm blocks + 1 scan.
#define BM 64
#define BN 128
#define BK 32
#define APAD 40   // row stride in shorts (80B)
#define GY ((N_NODES + BM - 1) / BM)            // 313
#define GEMM_BLOCKS (2 * GY)                    // 626
__global__ __launch_bounds__(256) void gemm1_kernel(
    const float* __restrict__ X, const unsigned short* __restrict__ BT,
    const float* __restrict__ bias, unsigned short* __restrict__ C,
    const int* __restrict__ deg, int* __restrict__ offs, int* __restrict__ cursor) {
  if (blockIdx.x >= GEMM_BLOCKS) {
    // ---- CSR exclusive scan: 250 threads x 80 nodes, register-buffered ----
    __shared__ int wsum[4];
    int t = threadIdx.x;
    int4 buf[20];
    int s = 0;
    if (t < 250) {
      const int4* dp = (const int4*)deg + t * 20;
#pragma unroll
      for (int i = 0; i < 20; i++) {
        buf[i] = dp[i];                      // independent loads — pipelined
        s += buf[i].x + buf[i].y + buf[i].z + buf[i].w;
      }
    }
    int lane = t & 63, w = t >> 6;
    int inc = s;
    for (int o = 1; o < 64; o <<= 1) {
      int u = __shfl_up(inc, o, 64);
      if (lane >= o) inc += u;
    }
    if (lane == 63) wsum[w] = inc;
    __syncthreads();
    int waveOff = 0;
    for (int i = 0; i < w; i++) waveOff += wsum[i];
    int running = waveOff + inc - s;         // exclusive thread offset
    if (t < 250) {
      int base = t * 80;
#pragma unroll
      for (int i = 0; i < 20; i++) {
        int4 v = buf[i];
        int4 o;
        o.x = running;
        o.y = o.x + v.x;
        o.z = o.y + v.y;
        o.w = o.z + v.z;
        running = o.w + v.w;
        *(int4*)(offs + base + i * 4) = o;
        *(int4*)(cursor + base + i * 4) = o;
      }
    }
    if (t == 0) offs[N_NODES] = ET;
    return;
  }
  // ---- GEMM tile ----
  __shared__ unsigned short As[BM][APAD];   // [64][40]
  __shared__ unsigned short Bs[BN][APAD];   // [128][40]
  const int tid = threadIdx.x;
  const int lane = tid & 63, wave = tid >> 6;
  const int wm = (wave & 1) * 32;
  const int wn = (wave >> 1) * 64;
  const int r16 = lane & 15, q = lane >> 4;
  const int bx = blockIdx.x & 1, by = blockIdx.x >> 1;
  const int rowBase = by * BM;
  const int colBase = bx * BN;
  floatx4 acc[2][4] = {};

  for (int k0 = 0; k0 < IN_C; k0 += BK) {
    // stage A from f32 x, converting to bf16: 64 rows x 32 k
    {
      int row = tid >> 2, kc = (tid & 3) * 8;
      int arow = rowBase + row;
      float4 v0 = make_float4(0.f, 0.f, 0.f, 0.f), v1 = v0;
      if (arow < N_NODES) {
        const float* p = X + (size_t)arow * IN_C + k0 + kc;
        v0 = *(const float4*)p;
        v1 = *(const float4*)(p + 4);
      }
      unsigned short tmp[8] = {f2bf(v0.x), f2bf(v0.y), f2bf(v0.z), f2bf(v0.w),
                               f2bf(v1.x), f2bf(v1.y), f2bf(v1.z), f2bf(v1.w)};
      *(float4*)&As[row][kc] = *(const float4*)tmp;
    }
    // stage B (bf16): 128 rows x 32 k -> 2 chunks per thread
#pragma unroll
    for (int i = 0; i < 2; i++) {
      int c = tid + i * 256;
      int row = c >> 2, kc = (c & 3) * 8;
      float4 v = *(const float4*)(BT + (size_t)(colBase + row) * IN_C + k0 + kc);
      *(float4*)&Bs[row][kc] = v;
    }
    __syncthreads();
    short8 afrag[2], bfrag[4];
#pragma unroll
    for (int mt = 0; mt < 2; mt++)
      afrag[mt] = *(const short8*)&As[wm + mt * 16 + r16][q * 8];
#pragma unroll
    for (int nt = 0; nt < 4; nt++)
      bfrag[nt] = *(const short8*)&Bs[wn + nt * 16 + r16][q * 8];
#pragma unroll
    for (int mt = 0; mt < 2; mt++)
#pragma unroll
      for (int nt = 0; nt < 4; nt++)
        acc[mt][nt] = __builtin_amdgcn_mfma_f32_16x16x32_bf16(
            afrag[mt], bfrag[nt], acc[mt][nt], 0, 0, 0);
    __syncthreads();
  }
#pragma unroll
  for (int mt = 0; mt < 2; mt++) {
#pragma unroll
    for (int nt = 0; nt < 4; nt++) {
      int col = colBase + wn + nt * 16 + r16;
      float bb = bias[col];
#pragma unroll
      for (int r = 0; r < 4; r++) {
        int row = rowBase + wm + mt * 16 + q * 4 + r;
        if (row < N_NODES) C[(size_t)row * HH + col] = f2bf(acc[mt][nt][r] + bb);
      }
    }
  }
}

// ================= L3: CSR fill + attn1 (wave-per-node dots) =================
#define FILL_BLOCKS ((ET + 255) / 256)          // 1329
#define ATTN1_BLOCKS (N_NODES / 4)              // 5000
__global__ __launch_bounds__(256) void fill_attn1_kernel(
    const int* __restrict__ ei, int* __restrict__ cursor, int* __restrict__ csr,
    const unsigned short* __restrict__ h1b, const float* __restrict__ asrc,
    const float* __restrict__ adst, float* __restrict__ as1, float* __restrict__ ad1) {
  if (blockIdx.x < FILL_BLOCKS) {
    int e = blockIdx.x * 256 + threadIdx.x;
    if (e >= ET) return;
    int src, dst;
    if (e < N_EDGES) { src = ei[e]; dst = ei[N_EDGES + e]; }
    else { src = e - N_EDGES; dst = src; }
    int pos = atomicAdd(&cursor[dst], 1);
    csr[pos] = src;
  } else {
    int wave = threadIdx.x >> 6, lane = threadIdx.x & 63;
    int n = (blockIdx.x - FILL_BLOCKS) * 4 + wave;   // exact: 5000*4 = 20000
    int c4 = lane * 4;
    uint2 raw = *(const uint2*)(h1b + (size_t)n * HH + c4);
    float h0 = bf2f_lo(raw.x), h1 = bf2f_hi(raw.x);
    float h2 = bf2f_lo(raw.y), h3 = bf2f_hi(raw.y);
    float4 sa = *(const float4*)(asrc + c4);
    float4 sd = *(const float4*)(adst + c4);
    float ps = h0 * sa.x + h1 * sa.y + h2 * sa.z + h3 * sa.w;
    float pd = h0 * sd.x + h1 * sd.y + h2 * sd.z + h3 * sd.w;
#pragma unroll
    for (int o = 4; o > 0; o >>= 1) {
      ps += __shfl_down(ps, o, 8);
      pd += __shfl_down(pd, o, 8);
    }
    if ((lane & 7) == 0) {
      as1[n * HEADS + (lane >> 3)] = ps;
      ad1[n * HEADS + (lane >> 3)] = pd;
    }
  }
}

// ================= L4: agg1 (max-free softmax + gather + bias + ELU) =========
__global__ __launch_bounds__(256) void agg1_kernel(
    const unsigned short* __restrict__ h1b, const float* __restrict__ as1,
    const float* __restrict__ ad1, const int* __restrict__ offs,
    const int* __restrict__ csr, const float* __restrict__ b1,
    float* __restrict__ h2) {
  int n = blockIdx.x * 4 + (threadIdx.x >> 6);
  int lane = threadIdx.x & 63;
  int half = lane >> 5;
  int sl = lane & 31;
  int c8 = sl * 8;
  int head = sl >> 2;
  int beg = offs[n], end = offs[n + 1];
  float ad = ad1[n * HEADS + head];
  float acc[8] = {};
  float l = 0.f;
#pragma unroll 2
  for (int k = beg + half; k < end; k += 2) {
    int src = csr[k];
    float e = as1[src * HEADS + head] + ad;
    e = (e > 0.f) ? e : NEG_SLOPE * e;
    float p = __expf(e);
    l += p;
    uint4 raw = *(const uint4*)(h1b + (size_t)src * HH + c8);
    acc[0] = fmaf(p, bf2f_lo(raw.x), acc[0]);
    acc[1] = fmaf(p, bf2f_hi(raw.x), acc[1]);
    acc[2] = fmaf(p, bf2f_lo(raw.y), acc[2]);
    acc[3] = fmaf(p, bf2f_hi(raw.y), acc[3]);
    acc[4] = fmaf(p, bf2f_lo(raw.z), acc[4]);
    acc[5] = fmaf(p, bf2f_hi(raw.z), acc[5]);
    acc[6] = fmaf(p, bf2f_lo(raw.w), acc[6]);
    acc[7] = fmaf(p, bf2f_hi(raw.w), acc[7]);
  }
#pragma unroll
  for (int j = 0; j < 8; j++) acc[j] += __shfl_xor(acc[j], 32, 64);
  l += __shfl_xor(l, 32, 64);
  if (half == 0) {
    float li = 1.f / (l + 1e-16f);
    float4 b0 = *(const float4*)(b1 + c8);
    float4 b4 = *(const float4*)(b1 + c8 + 4);
    float v[8];
    v[0] = acc[0] * li + b0.x; v[1] = acc[1] * li + b0.y;
    v[2] = acc[2] * li + b0.z; v[3] = acc[3] * li + b0.w;
    v[4] = acc[4] * li + b4.x; v[5] = acc[5] * li + b4.y;
    v[6] = acc[6] * li + b4.z; v[7] = acc[7] * li + b4.w;
#pragma unroll
    for (int j = 0; j < 8; j++) v[j] = (v[j] > 0.f) ? v[j] : expm1f(v[j]);
    *(float4*)(h2 + (size_t)n * HH + c8) = make_float4(v[0], v[1], v[2], v[3]);
    *(float4*)(h2 + (size_t)n * HH + c8 + 4) = make_float4(v[4], v[5], v[6], v[7]);
  }
}

// ================= L5: GEMM2 + attn2 fused ===================================
__global__ __launch_bounds__(320) void gemm2_kernel(
    const float* __restrict__ h2, const float* __restrict__ w2,
    const float* __restrict__ b2, const float* __restrict__ asrc2,
    const float* __restrict__ adst2, float* __restrict__ h3,
    float* __restrict__ as2, float* __restrict__ ad2) {
  __shared__ float hs[32 * 257];
  __shared__ float ws2[HH * OUT_C];
  int t = threadIdx.x;
  int nodeBase = blockIdx.x * 32;
  const float* src = h2 + (size_t)nodeBase * HH;
  for (int idx = t; idx < 32 * 256; idx += 320) {
    int n = idx >> 8, k = idx & 255;
    hs[n * 257 + k] = src[idx];
  }
  for (int idx = t; idx < HH * OUT_C; idx += 320) ws2[idx] = w2[idx];
  __syncthreads();
  int c = t % OUT_C;
  int ng = t / OUT_C;
  float acc[4] = {0.f, 0.f, 0.f, 0.f};
  for (int k = 0; k < HH; k++) {
    float w = ws2[k * OUT_C + c];
#pragma unroll
    for (int i = 0; i < 4; i++) acc[i] += hs[(ng * 4 + i) * 257 + k] * w;
  }
  float bb = b2[c];
  float sa = asrc2[c], sd = adst2[c];
  float v[4];
#pragma unroll
  for (int i = 0; i < 4; i++) {
    v[i] = acc[i] + bb;
    h3[(size_t)(nodeBase + ng * 4 + i) * OUT_C + c] = v[i];
  }
  __syncthreads();                  // all hs reads done; safe to reuse
  float* sp = hs;                   // [40][32]
  float* sd2 = hs + OUT_C * 32;     // [40][32]
#pragma unroll
  for (int i = 0; i < 4; i++) {
    sp[c * 32 + ng * 4 + i] = v[i] * sa;
    sd2[c * 32 + ng * 4 + i] = v[i] * sd;
  }
  __syncthreads();
  if (t < 32) {
    float ss = 0.f, dd = 0.f;
    for (int cc = 0; cc < OUT_C; cc++) {
      ss += sp[cc * 32 + t];
      dd += sd2[cc * 32 + t];
    }
    as2[nodeBase + t] = ss;
    ad2[nodeBase + t] = dd;
  }
}

// ================= L6: agg2 (max-free softmax + gather) + log_softmax ========
__global__ __launch_bounds__(256) void agg2_kernel(
    const float* __restrict__ h3, const float* __restrict__ as2,
    const float* __restrict__ ad2, const int* __restrict__ offs,
    const int* __restrict__ csr, const float* __restrict__ b2,
    float* __restrict__ out) {
  int n = blockIdx.x * 4 + (threadIdx.x >> 6);
  int t = threadIdx.x & 63;
  bool act = (t < OUT_C);
  int beg = offs[n], end = offs[n + 1];
  float ad = ad2[n];
  float l = 0.f, acc = 0.f;
#pragma unroll 2
  for (int k = beg; k < end; k++) {
    int src = csr[k];
    float e = as2[src] + ad;
    e = (e > 0.f) ? e : NEG_SLOPE * e;
    float p = __expf(e);
    l += p;
    float hv = act ? h3[(size_t)src * OUT_C + t] : 0.f;
    acc = fmaf(p, hv, acc);
  }
  float v = acc / (l + 1e-16f) + (act ? b2[t] : 0.f);
  float x = act ? v : -INFINITY;
  float mx = x;
  for (int o = 32; o > 0; o >>= 1) mx = fmaxf(mx, __shfl_down(mx, o, 64));
  mx = __shfl(mx, 0, 64);
  float ex = act ? __expf(v - mx) : 0.f;
  float s = ex;
  for (int o = 32; o > 0; o >>= 1) s += __shfl_down(s, o, 64);
  s = __shfl(s, 0, 64);
  if (act) out[(size_t)n * OUT_C + t] = v - mx - logf(s);
}

extern "C" void kernel_launch(void* const* d_in, const int* in_sizes, int n_in,
                              void* d_out, int out_size, void* d_ws, size_t ws_size,
                              hipStream_t stream) {
  const float* x     = (const float*)d_in[0];
  const int*   ei    = (const int*)d_in[1];
  const float* w1    = (const float*)d_in[2];
  const float* asrc1 = (const float*)d_in[3];
  const float* adst1 = (const float*)d_in[4];
  const float* b1    = (const float*)d_in[5];
  const float* w2    = (const float*)d_in[6];
  const float* asrc2 = (const float*)d_in[7];
  const float* adst2 = (const float*)d_in[8];
  const float* b2    = (const float*)d_in[9];
  float* out = (float*)d_out;

  // workspace carve-up (~37 MB). deg is 16B-aligned (all prior extents are
  // multiples of 4 floats); cursor padded to stay 16B-aligned for int4 stores.
  float* fw = (float*)d_ws;
  float* as1   = fw;  fw += (size_t)N_NODES * HEADS;
  float* ad1   = fw;  fw += (size_t)N_NODES * HEADS;
  float* h2    = fw;  fw += (size_t)N_NODES * HH;
  float* h3    = fw;  fw += (size_t)N_NODES * OUT_C;
  float* as2   = fw;  fw += N_NODES;
  float* ad2   = fw;  fw += N_NODES;
  unsigned short* h1b = (unsigned short*)fw;  fw += (size_t)N_NODES * HH / 2;
  unsigned short* wbT = (unsigned short*)fw;  fw += (size_t)IN_C * HH / 2;
  int* deg    = (int*)fw;
  int* offs   = deg + N_NODES;            // N+1 (+3 pad)
  int* cursor = offs + N_NODES + 4;       // 16B-aligned
  int* csr    = cursor + N_NODES;         // ET

  hipMemsetAsync(deg, 0, N_NODES * sizeof(int), stream);

  prep_kernel<<<WCONV_BLOCKS + COUNT_BLOCKS, 256, 0, stream>>>(w1, ei, wbT, deg);
  gemm1_kernel<<<GEMM_BLOCKS + 1, 256, 0, stream>>>(x, wbT, b1, h1b, deg, offs, cursor);
  fill_attn1_kernel<<<FILL_BLOCKS + ATTN1_BLOCKS, 256, 0, stream>>>(
      ei, cursor, csr, h1b, asrc1, adst1, as1, ad1);
  agg1_kernel<<<N_NODES / 4, 256, 0, stream>>>(h1b, as1, ad1, offs, csr, b1, h2);
  gemm2_kernel<<<N_NODES / 32, 320, 0, stream>>>(h2, w2, b2, asrc2, adst2, h3, as2, ad2);
  agg2_kernel<<<N_NODES / 4, 256, 0, stream>>>(h3, as2, ad2, offs, csr, b2, out);
}

// Round 7
// 232.808 us; speedup vs baseline: 1.4856x; 1.0426x over previous
//
#include <hip/hip_runtime.h>
#include <hip/hip_bf16.h>
#include <math.h>

#define N_NODES 20000
#define N_EDGES 320000
#define ET (N_EDGES + N_NODES)   // with self loops = 340000
#define IN_C 512
#define HEADS 8
#define HID 32
#define HH (HEADS * HID)         // 256
#define OUT_C 40
#define NEG_SLOPE 0.2f

typedef __attribute__((ext_vector_type(8))) short short8;
typedef __attribute__((ext_vector_type(4))) float floatx4;

static __device__ __forceinline__ unsigned short f2bf(float f) {
  __hip_bfloat16 h = __float2bfloat16(f);
  return *(unsigned short*)&h;
}
static __device__ __forceinline__ float bf2f_lo(unsigned int u) {
  return __uint_as_float(u << 16);
}
static __device__ __forceinline__ float bf2f_hi(unsigned int u) {
  return __uint_as_float(u & 0xFFFF0000u);
}

// ================= L1: w1/w2 -> bf16 (w2 transposed)  +  edge count ==========
#define WCONV_BLOCKS (IN_C * HH / 256)          // 512
#define W2CONV_BLOCKS (HH * OUT_C / 256)        // 40
#define COUNT_BLOCKS ((ET + 255) / 256)         // 1329
__global__ __launch_bounds__(256) void prep_kernel(
    const float* __restrict__ w1, const float* __restrict__ w2,
    const int* __restrict__ ei, unsigned short* __restrict__ wbT,
    unsigned short* __restrict__ w2bT, int* __restrict__ deg) {
  if (blockIdx.x < WCONV_BLOCKS) {
    int j = blockIdx.x * 256 + threadIdx.x;     // coalesced read of w1
    int k = j >> 8, n = j & 255;
    wbT[(size_t)n * IN_C + k] = f2bf(w1[j]);
  } else if (blockIdx.x < WCONV_BLOCKS + W2CONV_BLOCKS) {
    int j = (blockIdx.x - WCONV_BLOCKS) * 256 + threadIdx.x;  // 10240
    int k = j / OUT_C, oc = j % OUT_C;
    w2bT[oc * HH + k] = f2bf(w2[j]);
  } else {
    int e = (blockIdx.x - WCONV_BLOCKS - W2CONV_BLOCKS) * 256 + threadIdx.x;
    if (e < ET) {
      int dst = (e < N_EDGES) ? ei[N_EDGES + e] : (e - N_EDGES);
      atomicAdd(&deg[dst], 1);
    }
  }
}

// ================= L2: GEMM1 (MFMA bf16, f32 A staged+converted) + CSR scan ==
#define BM 64
#define BN 128
#define BK 32
#define APAD 40   // row stride in shorts (80B)
#define GY ((N_NODES + BM - 1) / BM)            // 313
#define GEMM_BLOCKS (2 * GY)                    // 626
__global__ __launch_bounds__(256) void gemm1_kernel(
    const float* __restrict__ X, const unsigned short* __restrict__ BT,
    const float* __restrict__ bias, unsigned short* __restrict__ C,
    const int* __restrict__ deg, int* __restrict__ offs, int* __restrict__ cursor) {
  if (blockIdx.x >= GEMM_BLOCKS) {
    // ---- CSR exclusive scan: 250 threads x 80 nodes, register-buffered ----
    __shared__ int wsum[4];
    int t = threadIdx.x;
    int4 buf[20];
    int s = 0;
    if (t < 250) {
      const int4* dp = (const int4*)deg + t * 20;
#pragma unroll
      for (int i = 0; i < 20; i++) {
        buf[i] = dp[i];                      // independent loads — pipelined
        s += buf[i].x + buf[i].y + buf[i].z + buf[i].w;
      }
    }
    int lane = t & 63, w = t >> 6;
    int inc = s;
    for (int o = 1; o < 64; o <<= 1) {
      int u = __shfl_up(inc, o, 64);
      if (lane >= o) inc += u;
    }
    if (lane == 63) wsum[w] = inc;
    __syncthreads();
    int waveOff = 0;
    for (int i = 0; i < w; i++) waveOff += wsum[i];
    int running = waveOff + inc - s;         // exclusive thread offset
    if (t < 250) {
      int base = t * 80;
#pragma unroll
      for (int i = 0; i < 20; i++) {
        int4 v = buf[i];
        int4 o;
        o.x = running;
        o.y = o.x + v.x;
        o.z = o.y + v.y;
        o.w = o.z + v.z;
        running = o.w + v.w;
        *(int4*)(offs + base + i * 4) = o;
        *(int4*)(cursor + base + i * 4) = o;
      }
    }
    if (t == 0) offs[N_NODES] = ET;
    return;
  }
  // ---- GEMM tile ----
  __shared__ unsigned short As[BM][APAD];   // [64][40]
  __shared__ unsigned short Bs[BN][APAD];   // [128][40]
  const int tid = threadIdx.x;
  const int lane = tid & 63, wave = tid >> 6;
  const int wm = (wave & 1) * 32;
  const int wn = (wave >> 1) * 64;
  const int r16 = lane & 15, q = lane >> 4;
  const int bx = blockIdx.x & 1, by = blockIdx.x >> 1;
  const int rowBase = by * BM;
  const int colBase = bx * BN;
  floatx4 acc[2][4] = {};

  for (int k0 = 0; k0 < IN_C; k0 += BK) {
    {
      int row = tid >> 2, kc = (tid & 3) * 8;
      int arow = rowBase + row;
      float4 v0 = make_float4(0.f, 0.f, 0.f, 0.f), v1 = v0;
      if (arow < N_NODES) {
        const float* p = X + (size_t)arow * IN_C + k0 + kc;
        v0 = *(const float4*)p;
        v1 = *(const float4*)(p + 4);
      }
      unsigned short tmp[8] = {f2bf(v0.x), f2bf(v0.y), f2bf(v0.z), f2bf(v0.w),
                               f2bf(v1.x), f2bf(v1.y), f2bf(v1.z), f2bf(v1.w)};
      *(float4*)&As[row][kc] = *(const float4*)tmp;
    }
#pragma unroll
    for (int i = 0; i < 2; i++) {
      int c = tid + i * 256;
      int row = c >> 2, kc = (c & 3) * 8;
      float4 v = *(const float4*)(BT + (size_t)(colBase + row) * IN_C + k0 + kc);
      *(float4*)&Bs[row][kc] = v;
    }
    __syncthreads();
    short8 afrag[2], bfrag[4];
#pragma unroll
    for (int mt = 0; mt < 2; mt++)
      afrag[mt] = *(const short8*)&As[wm + mt * 16 + r16][q * 8];
#pragma unroll
    for (int nt = 0; nt < 4; nt++)
      bfrag[nt] = *(const short8*)&Bs[wn + nt * 16 + r16][q * 8];
#pragma unroll
    for (int mt = 0; mt < 2; mt++)
#pragma unroll
      for (int nt = 0; nt < 4; nt++)
        acc[mt][nt] = __builtin_amdgcn_mfma_f32_16x16x32_bf16(
            afrag[mt], bfrag[nt], acc[mt][nt], 0, 0, 0);
    __syncthreads();
  }
#pragma unroll
  for (int mt = 0; mt < 2; mt++) {
#pragma unroll
    for (int nt = 0; nt < 4; nt++) {
      int col = colBase + wn + nt * 16 + r16;
      float bb = bias[col];
#pragma unroll
      for (int r = 0; r < 4; r++) {
        int row = rowBase + wm + mt * 16 + q * 4 + r;
        if (row < N_NODES) C[(size_t)row * HH + col] = f2bf(acc[mt][nt][r] + bb);
      }
    }
  }
}

// ================= L3: CSR fill + attn1 (wave-per-node dots) =================
#define FILL_BLOCKS ((ET + 255) / 256)          // 1329
#define ATTN1_BLOCKS (N_NODES / 4)              // 5000
__global__ __launch_bounds__(256) void fill_attn1_kernel(
    const int* __restrict__ ei, int* __restrict__ cursor, int* __restrict__ csr,
    const unsigned short* __restrict__ h1b, const float* __restrict__ asrc,
    const float* __restrict__ adst, float* __restrict__ as1, float* __restrict__ ad1) {
  if (blockIdx.x < FILL_BLOCKS) {
    int e = blockIdx.x * 256 + threadIdx.x;
    if (e >= ET) return;
    int src, dst;
    if (e < N_EDGES) { src = ei[e]; dst = ei[N_EDGES + e]; }
    else { src = e - N_EDGES; dst = src; }
    int pos = atomicAdd(&cursor[dst], 1);
    csr[pos] = src;
  } else {
    int wave = threadIdx.x >> 6, lane = threadIdx.x & 63;
    int n = (blockIdx.x - FILL_BLOCKS) * 4 + wave;   // exact: 5000*4 = 20000
    int c4 = lane * 4;
    uint2 raw = *(const uint2*)(h1b + (size_t)n * HH + c4);
    float h0 = bf2f_lo(raw.x), h1 = bf2f_hi(raw.x);
    float h2 = bf2f_lo(raw.y), h3 = bf2f_hi(raw.y);
    float4 sa = *(const float4*)(asrc + c4);
    float4 sd = *(const float4*)(adst + c4);
    float ps = h0 * sa.x + h1 * sa.y + h2 * sa.z + h3 * sa.w;
    float pd = h0 * sd.x + h1 * sd.y + h2 * sd.z + h3 * sd.w;
#pragma unroll
    for (int o = 4; o > 0; o >>= 1) {
      ps += __shfl_down(ps, o, 8);
      pd += __shfl_down(pd, o, 8);
    }
    if ((lane & 7) == 0) {
      as1[n * HEADS + (lane >> 3)] = ps;
      ad1[n * HEADS + (lane >> 3)] = pd;
    }
  }
}

// ================= L4: fused agg1 + GEMM2 + attn2 ============================
// 4 waves/block, one wave per node. Phase A: max-free softmax gather -> h2 row
// (registers). Phase B: h2 row via LDS x w2 (bf16 LDS) -> h3 + as2/ad2.
#define W2ROW 260    // padded row stride (shorts) for w2s; 520B, 8B-aligned
#define HROW 260     // padded row stride (floats) for hrow; 1040B, 16B-aligned
__global__ __launch_bounds__(256) void layer1_fused_kernel(
    const unsigned short* __restrict__ h1b, const float* __restrict__ as1,
    const float* __restrict__ ad1, const int* __restrict__ offs,
    const int* __restrict__ csr, const float* __restrict__ b1,
    const unsigned short* __restrict__ w2bT, const float* __restrict__ b2,
    const float* __restrict__ asrc2, const float* __restrict__ adst2,
    float* __restrict__ h3, float* __restrict__ as2, float* __restrict__ ad2) {
  __shared__ unsigned short w2s[OUT_C * W2ROW];   // 20800 B
  __shared__ float hrow[4][HROW];                 // 4160 B
  const int tid = threadIdx.x;
  // stage w2bT [40][256] bf16 -> LDS (padded rows): 2560 uint2 chunks
#pragma unroll
  for (int i = 0; i < 10; i++) {
    int c = tid + i * 256;
    int row = c >> 6, off = c & 63;           // 64 uint2 per row
    *(uint2*)&w2s[row * W2ROW + off * 4] = *(const uint2*)(w2bT + row * HH + off * 4);
  }

  // ---- Phase A: agg1 gather ----
  int wave = tid >> 6, lane = tid & 63;
  int n = blockIdx.x * 4 + wave;
  int half = lane >> 5;
  int sl = lane & 31;
  int c8 = sl * 8;
  int head = sl >> 2;
  int beg = offs[n], end = offs[n + 1];
  float ad = ad1[n * HEADS + head];
  float acc[8] = {};
  float l = 0.f;
#pragma unroll 2
  for (int k = beg + half; k < end; k += 2) {
    int src = csr[k];
    float e = as1[src * HEADS + head] + ad;
    e = (e > 0.f) ? e : NEG_SLOPE * e;
    float p = __expf(e);
    l += p;
    uint4 raw = *(const uint4*)(h1b + (size_t)src * HH + c8);
    acc[0] = fmaf(p, bf2f_lo(raw.x), acc[0]);
    acc[1] = fmaf(p, bf2f_hi(raw.x), acc[1]);
    acc[2] = fmaf(p, bf2f_lo(raw.y), acc[2]);
    acc[3] = fmaf(p, bf2f_hi(raw.y), acc[3]);
    acc[4] = fmaf(p, bf2f_lo(raw.z), acc[4]);
    acc[5] = fmaf(p, bf2f_hi(raw.z), acc[5]);
    acc[6] = fmaf(p, bf2f_lo(raw.w), acc[6]);
    acc[7] = fmaf(p, bf2f_hi(raw.w), acc[7]);
  }
#pragma unroll
  for (int j = 0; j < 8; j++) acc[j] += __shfl_xor(acc[j], 32, 64);
  l += __shfl_xor(l, 32, 64);
  if (half == 0) {
    float li = 1.f / (l + 1e-16f);
    float4 b0 = *(const float4*)(b1 + c8);
    float4 b4 = *(const float4*)(b1 + c8 + 4);
    float v[8];
    v[0] = acc[0] * li + b0.x; v[1] = acc[1] * li + b0.y;
    v[2] = acc[2] * li + b0.z; v[3] = acc[3] * li + b0.w;
    v[4] = acc[4] * li + b4.x; v[5] = acc[5] * li + b4.y;
    v[6] = acc[6] * li + b4.z; v[7] = acc[7] * li + b4.w;
#pragma unroll
    for (int j = 0; j < 8; j++) v[j] = (v[j] > 0.f) ? v[j] : expm1f(v[j]);  // ELU
    *(float4*)&hrow[wave][c8] = make_float4(v[0], v[1], v[2], v[3]);
    *(float4*)&hrow[wave][c8 + 4] = make_float4(v[4], v[5], v[6], v[7]);
  }
  __syncthreads();

  // ---- Phase B: h3[n][oc] = hrow[n] . w2[:,oc] + b2; attn2 dots ----
  float val = 0.f, ps = 0.f, pd = 0.f;
  if (lane < OUT_C) {
    float hacc = 0.f;
#pragma unroll 8
    for (int g = 0; g < HH / 4; g++) {
      float4 hv = *(const float4*)&hrow[wave][g * 4];                 // broadcast
      uint2 wv = *(const uint2*)&w2s[lane * W2ROW + g * 4];           // 4 bf16
      hacc += hv.x * bf2f_lo(wv.x) + hv.y * bf2f_hi(wv.x)
            + hv.z * bf2f_lo(wv.y) + hv.w * bf2f_hi(wv.y);
    }
    val = hacc + b2[lane];
    h3[(size_t)n * OUT_C + lane] = val;
    ps = val * asrc2[lane];
    pd = val * adst2[lane];
  }
#pragma unroll
  for (int o = 32; o > 0; o >>= 1) {
    ps += __shfl_down(ps, o, 64);
    pd += __shfl_down(pd, o, 64);
  }
  if (lane == 0) { as2[n] = ps; ad2[n] = pd; }
}

// ================= L5: agg2 (max-free softmax + gather) + log_softmax ========
__global__ __launch_bounds__(256) void agg2_kernel(
    const float* __restrict__ h3, const float* __restrict__ as2,
    const float* __restrict__ ad2, const int* __restrict__ offs,
    const int* __restrict__ csr, const float* __restrict__ b2,
    float* __restrict__ out) {
  int n = blockIdx.x * 4 + (threadIdx.x >> 6);
  int t = threadIdx.x & 63;
  bool act = (t < OUT_C);
  int beg = offs[n], end = offs[n + 1];
  float ad = ad2[n];
  float l = 0.f, acc = 0.f;
#pragma unroll 2
  for (int k = beg; k < end; k++) {
    int src = csr[k];
    float e = as2[src] + ad;
    e = (e > 0.f) ? e : NEG_SLOPE * e;
    float p = __expf(e);
    l += p;
    float hv = act ? h3[(size_t)src * OUT_C + t] : 0.f;
    acc = fmaf(p, hv, acc);
  }
  float v = acc / (l + 1e-16f) + (act ? b2[t] : 0.f);
  float x = act ? v : -INFINITY;
  float mx = x;
  for (int o = 32; o > 0; o >>= 1) mx = fmaxf(mx, __shfl_down(mx, o, 64));
  mx = __shfl(mx, 0, 64);
  float ex = act ? __expf(v - mx) : 0.f;
  float s = ex;
  for (int o = 32; o > 0; o >>= 1) s += __shfl_down(s, o, 64);
  s = __shfl(s, 0, 64);
  if (act) out[(size_t)n * OUT_C + t] = v - mx - logf(s);
}

extern "C" void kernel_launch(void* const* d_in, const int* in_sizes, int n_in,
                              void* d_out, int out_size, void* d_ws, size_t ws_size,
                              hipStream_t stream) {
  const float* x     = (const float*)d_in[0];
  const int*   ei    = (const int*)d_in[1];
  const float* w1    = (const float*)d_in[2];
  const float* asrc1 = (const float*)d_in[3];
  const float* adst1 = (const float*)d_in[4];
  const float* b1    = (const float*)d_in[5];
  const float* w2    = (const float*)d_in[6];
  const float* asrc2 = (const float*)d_in[7];
  const float* adst2 = (const float*)d_in[8];
  const float* b2    = (const float*)d_in[9];
  float* out = (float*)d_out;

  // workspace carve-up. All extents keep 16B alignment for int4/float4 ops.
  float* fw = (float*)d_ws;
  float* as1   = fw;  fw += (size_t)N_NODES * HEADS;
  float* ad1   = fw;  fw += (size_t)N_NODES * HEADS;
  float* h3    = fw;  fw += (size_t)N_NODES * OUT_C;
  float* as2   = fw;  fw += N_NODES;
  float* ad2   = fw;  fw += N_NODES;
  unsigned short* h1b  = (unsigned short*)fw;  fw += (size_t)N_NODES * HH / 2;
  unsigned short* wbT  = (unsigned short*)fw;  fw += (size_t)IN_C * HH / 2;
  unsigned short* w2bT = (unsigned short*)fw;  fw += (size_t)HH * OUT_C / 2;
  int* deg    = (int*)fw;
  int* offs   = deg + N_NODES;            // N+1 (+3 pad)
  int* cursor = offs + N_NODES + 4;       // 16B-aligned
  int* csr    = cursor + N_NODES;         // ET

  hipMemsetAsync(deg, 0, N_NODES * sizeof(int), stream);

  prep_kernel<<<WCONV_BLOCKS + W2CONV_BLOCKS + COUNT_BLOCKS, 256, 0, stream>>>(
      w1, w2, ei, wbT, w2bT, deg);
  gemm1_kernel<<<GEMM_BLOCKS + 1, 256, 0, stream>>>(x, wbT, b1, h1b, deg, offs, cursor);
  fill_attn1_kernel<<<FILL_BLOCKS + ATTN1_BLOCKS, 256, 0, stream>>>(
      ei, cursor, csr, h1b, asrc1, adst1, as1, ad1);
  layer1_fused_kernel<<<N_NODES / 4, 256, 0, stream>>>(
      h1b, as1, ad1, offs, csr, b1, w2bT, b2, asrc2, adst2, h3, as2, ad2);
  agg2_kernel<<<N_NODES / 4, 256, 0, stream>>>(h3, as2, ad2, offs, csr, b2, out);
}